// Round 1
// baseline (708.732 us; speedup 1.0000x reference)
//
#include <hip/hip_runtime.h>

#define TOKENS 8192
#define HIDDEN 2048
#define INTER  5632

typedef _Float16 f16x8 __attribute__((ext_vector_type(8)));
typedef float    f32x4 __attribute__((ext_vector_type(4)));

// async global->LDS, 16B per lane. LDS dest = wave-uniform base + lane*16.
__device__ __forceinline__ void async_copy16(const void* g, void* l) {
  __builtin_amdgcn_global_load_lds(
      (const __attribute__((address_space(1))) unsigned int*)g,
      (__attribute__((address_space(3))) unsigned int*)l, 16, 0, 0);
}

#define BAR   __builtin_amdgcn_s_barrier()
#define SB0   __builtin_amdgcn_sched_barrier(0)
#define LGKM0 do { asm volatile("s_waitcnt lgkmcnt(0)" ::: "memory"); SB0; } while (0)
#define WAITVM(n) asm volatile("s_waitcnt vmcnt(" #n ")" ::: "memory")
#define PRIO(x) __builtin_amdgcn_s_setprio(x)

// ---------------- producers (unchanged, verified) ----------------

// x [T,H] fp32 -> staged [T/128][H/8][128][8] f16
__global__ void k_convert_x(const float* __restrict__ x, _Float16* __restrict__ xs) {
  const int kb = blockIdx.x;            // H/8 = 256
  const int mt = blockIdx.y;            // T/128 = 64
  const int m  = threadIdx.x;           // 128
  const float* src = x + (size_t)(mt * 128 + m) * HIDDEN + kb * 8;
  float4 f0 = *(const float4*)src;
  float4 f1 = *(const float4*)(src + 4);
  f16x8 v;
  v[0] = (_Float16)f0.x; v[1] = (_Float16)f0.y; v[2] = (_Float16)f0.z; v[3] = (_Float16)f0.w;
  v[4] = (_Float16)f1.x; v[5] = (_Float16)f1.y; v[6] = (_Float16)f1.z; v[7] = (_Float16)f1.w;
  *(f16x8*)(xs + ((size_t)(mt * 256 + kb) * 128 + m) * 8) = v;
}

// GPTQ dequant: qweight [K/8,N] int32 -> staged [K/8][N][8] f16
__global__ void k_dequant(const unsigned int* __restrict__ qw,
                          const unsigned int* __restrict__ qz,
                          const float* __restrict__ sc,
                          _Float16* __restrict__ out, int N, int N8) {
  const int n  = blockIdx.x * 256 + threadIdx.x;
  const int k8 = blockIdx.y;
  const int g  = k8 >> 4;
  unsigned int q  = qw[(size_t)k8 * N + n];
  unsigned int zw = qz[(size_t)g * N8 + (n >> 3)];
  int   z1 = (int)((zw >> ((n & 7) * 4)) & 0xFu) + 1;
  float s  = sc[(size_t)g * N + n];
  f16x8 w;
#pragma unroll
  for (int j = 0; j < 8; ++j)
    w[j] = (_Float16)((float)((int)((q >> (4 * j)) & 0xFu) - z1) * s);
  *(f16x8*)(out + ((size_t)k8 * N + n) * 8) = w;
}

// ---------------- GEMM1: 8-phase counted-vmcnt, tile 256x128, dual-B ----------------
// 512 thr = 8 waves (4M x 2N), per-wave 64x64 per matrix, BK=64, NT=32 K-tiles.
// LDS 128KB: A[2] 32KB each ([2 half][8 kb][128][8]), Bg[2]/Bu[2] 16KB each ([8kb][128][8]).
// Stage chunks/K-tile: A=4 loads/thr, Bg=2, Bu=2 (uniform across waves -> vmcnt valid).
// vmcnt ledger (steady state), issues per iter: ph1 Bu(O):2, ph2 A(E+2):4, ph3 Bg(E+2):2,
//   ph5 Bu(E+2):2, ph6 A(O+2):4, ph7 Bg(O+2):2.
//   ph4 WAITVM(6): leaves {A(E+2),Bg(E+2)} -> tile O fully resident before ph5 reads buf1.
//   ph8 WAITVM(6): leaves {A(O+2),Bg(O+2)} -> tile E+2 resident before next ph1 reads buf0.
// Stage-overwrite safety: every stage targets a region whose last ds_read was issued a
// phase earlier and completed at that phase's lgkmcnt(0), barrier-separated since.
__global__ __launch_bounds__(512, 1)
void k_gemm_gateup(const _Float16* __restrict__ xs,
                   const _Float16* __restrict__ wg,
                   const _Float16* __restrict__ wu,
                   _Float16* __restrict__ hs) {
  extern __shared__ _Float16 lds[];
  _Float16* A0  = lds;            // 16384 f16
  _Float16* A1  = lds + 16384;
  _Float16* Bg0 = lds + 32768;    // 8192 f16
  _Float16* Bg1 = lds + 40960;
  _Float16* Bu0 = lds + 49152;
  _Float16* Bu1 = lds + 57344;

  const int bid  = blockIdx.x;                    // 1408 = 44*32, %8==0
  const int wgid = (bid & 7) * 176 + (bid >> 3);  // XCD-chunked swizzle (bijective)
  const int mt = wgid / 44, nt = wgid % 44;       // consecutive wgid share mt (A-panel in L2)

  const int tid  = threadIdx.x;
  const int wave = tid >> 6, lane = tid & 63;
  const int wm = wave >> 1, wn = wave & 1;        // 4M x 2N
  const int row16 = lane >> 4, col = lane & 15;

  int afo[4], bfo[4];
#pragma unroll
  for (int i = 0; i < 4; ++i) {
    afo[i] = (wm >> 1) * 8192 + row16 * 1024 + ((wm & 1) * 64 + i * 16 + col) * 8;
    bfo[i] = row16 * 1024 + (wn * 64 + i * 16 + col) * 8;
  }

  const f32x4 zero = {0.f, 0.f, 0.f, 0.f};
  f32x4 accg[4][4], accu[4][4];
#pragma unroll
  for (int i = 0; i < 4; ++i)
#pragma unroll
    for (int j = 0; j < 4; ++j) { accg[i][j] = zero; accu[i][j] = zero; }

  f16x8 af[4][2], bf[2][2];

#define GU_LOAD_A(AP) \
  _Pragma("unroll") for (int mi_ = 0; mi_ < 4; ++mi_) \
  _Pragma("unroll") for (int ks_ = 0; ks_ < 2; ++ks_) \
    af[mi_][ks_] = *(const f16x8*)((AP) + afo[mi_] + ks_ * 4096);

#define GU_LOAD_B(BP, nh) \
  _Pragma("unroll") for (int ni_ = 0; ni_ < 2; ++ni_) \
  _Pragma("unroll") for (int ks_ = 0; ks_ < 2; ++ks_) \
    bf[ni_][ks_] = *(const f16x8*)((BP) + bfo[(nh) * 2 + ni_] + ks_ * 4096);

#define GU_MFMA(ACC, nh) \
  _Pragma("unroll") for (int mi_ = 0; mi_ < 4; ++mi_) \
  _Pragma("unroll") for (int ni_ = 0; ni_ < 2; ++ni_) \
  _Pragma("unroll") for (int ks_ = 0; ks_ < 2; ++ks_) \
    ACC[mi_][(nh) * 2 + ni_] = __builtin_amdgcn_mfma_f32_16x16x32_f16( \
        af[mi_][ks_], bf[ni_][ks_], ACC[mi_][(nh) * 2 + ni_], 0, 0, 0);

#define GU_STAGE_A(AP, kt) do { const int kt_ = (kt); \
  _Pragma("unroll") for (int q_ = 0; q_ < 4; ++q_) { \
    const int i_ = q_ * 512 + tid; \
    async_copy16(xs + (size_t)(((2 * mt + (i_ >> 10)) * 256 + kt_ * 8 + ((i_ >> 7) & 7)) * 128 + (i_ & 127)) * 8, \
                 (char*)(AP) + q_ * 8192 + wave * 1024); } } while (0)

#define GU_STAGE_B(BP, W, kt) do { const int kt_ = (kt); \
  _Pragma("unroll") for (int q_ = 0; q_ < 2; ++q_) { \
    const int i_ = q_ * 512 + tid; \
    async_copy16((W) + (size_t)((kt_ * 8 + (i_ >> 7)) * INTER + nt * 128 + (i_ & 127)) * 8, \
                 (char*)(BP) + q_ * 8192 + wave * 1024); } } while (0)

  // prologue: tile0 full -> buf0 (8 loads), tile1 A+Bg -> buf1 (6 loads); Bu(1) staged in ph1.
  GU_STAGE_A(A0, 0); GU_STAGE_B(Bg0, wg, 0); GU_STAGE_B(Bu0, wu, 0);
  GU_STAGE_A(A1, 1); GU_STAGE_B(Bg1, wg, 1);
  WAITVM(6);          // tile0 complete; A(1),Bg(1) stay in flight
  BAR; SB0;

  for (int t2 = 0; t2 < 16; ++t2) {
    const int O  = 2 * t2 + 1;
    const int e2 = (2 * t2 + 2 < 32) ? 2 * t2 + 2 : 31;   // clamped dummies keep vmcnt uniform
    const int o2 = (2 * t2 + 3 < 32) ? 2 * t2 + 3 : 31;
    // ph1: E gate nh0
    GU_LOAD_A(A0); GU_LOAD_B(Bg0, 0); GU_STAGE_B(Bu1, wu, O);
    BAR; LGKM0; PRIO(1); GU_MFMA(accg, 0); PRIO(0); BAR; SB0;
    // ph2: E gate nh1
    GU_LOAD_B(Bg0, 1); GU_STAGE_A(A0, e2);
    BAR; LGKM0; PRIO(1); GU_MFMA(accg, 1); PRIO(0); BAR; SB0;
    // ph3: E up nh0
    GU_LOAD_B(Bu0, 0); GU_STAGE_B(Bg0, wg, e2);
    BAR; LGKM0; PRIO(1); GU_MFMA(accu, 0); PRIO(0); BAR; SB0;
    // ph4: E up nh1 + counted wait (tile O resident)
    GU_LOAD_B(Bu0, 1);
    BAR; LGKM0; PRIO(1); GU_MFMA(accu, 1); PRIO(0); WAITVM(6); BAR; SB0;
    // ph5: O gate nh0
    GU_LOAD_A(A1); GU_LOAD_B(Bg1, 0); GU_STAGE_B(Bu0, wu, e2);
    BAR; LGKM0; PRIO(1); GU_MFMA(accg, 0); PRIO(0); BAR; SB0;
    // ph6: O gate nh1
    GU_LOAD_B(Bg1, 1); GU_STAGE_A(A1, o2);
    BAR; LGKM0; PRIO(1); GU_MFMA(accg, 1); PRIO(0); BAR; SB0;
    // ph7: O up nh0
    GU_LOAD_B(Bu1, 0); GU_STAGE_B(Bg1, wg, o2);
    BAR; LGKM0; PRIO(1); GU_MFMA(accu, 0); PRIO(0); BAR; SB0;
    // ph8: O up nh1 + counted wait (tile E+2 resident)
    GU_LOAD_B(Bu1, 1);
    BAR; LGKM0; PRIO(1); GU_MFMA(accu, 1); PRIO(0); WAITVM(6); BAR; SB0;
  }
  WAITVM(0);  // drain dummy stages before workgroup teardown

  // epilogue: h = silu(g)*u into staged [T/128][I/8][128][8]
  const size_t mt128 = (size_t)(2 * mt + (wm >> 1));
#pragma unroll
  for (int mi = 0; mi < 4; ++mi)
#pragma unroll
    for (int ni = 0; ni < 4; ++ni) {
      const int kg = nt * 128 + wn * 64 + ni * 16 + col;
      const size_t base = (mt128 * 704 + (size_t)(kg >> 3)) * 1024 + (kg & 7);
#pragma unroll
      for (int r = 0; r < 4; ++r) {
        const float g = accg[mi][ni][r], u = accu[mi][ni][r];
        const float h = g / (1.f + __expf(-g)) * u;
        const int mloc = (wm & 1) * 64 + mi * 16 + row16 * 4 + r;
        hs[base + (size_t)mloc * 8] = (_Float16)h;
      }
    }
#undef GU_LOAD_A
#undef GU_LOAD_B
#undef GU_MFMA
#undef GU_STAGE_A
#undef GU_STAGE_B
}

// ---------------- GEMM2: 8-phase counted-vmcnt, tile 256x256 (m201 geometry) ----------------
// 8 waves (2M x 4N), per-wave 128x64, BK=64, NT=88. LDS 128KB: A[2] 32KB, B[2] 32KB.
// Stage chunks: A=4 loads/thr, B=4. vmcnt ledger: ph3 B(E+2), ph4 A(E+2), ph7 B(O+2), ph8 A(O+2);
//   ph4 WAITVM(8) -> tile O resident; ph8 WAITVM(8) -> tile E+2 resident.
__global__ __launch_bounds__(512, 1)
void k_gemm_down(const _Float16* __restrict__ hs,
                 const _Float16* __restrict__ wd,
                 float* __restrict__ out) {
  extern __shared__ _Float16 lds[];
  _Float16* A0 = lds;            // [2 half][8 kb][128][8] = 16384 f16
  _Float16* A1 = lds + 16384;
  _Float16* B0 = lds + 32768;    // [8 kb][256][8] = 16384 f16
  _Float16* B1 = lds + 49152;

  const int bid  = blockIdx.x;                   // 256 = 8*32, %8==0
  const int wgid = (bid & 7) * 32 + (bid >> 3);  // XCD-chunked swizzle
  const int nt = wgid >> 5, mt = wgid & 31;      // each XCD chunk shares one B-panel (2.9MB, L2-fit)

  const int tid  = threadIdx.x;
  const int wave = tid >> 6, lane = tid & 63;
  const int wm = wave >> 2, wn = wave & 3;       // 2M x 4N
  const int row16 = lane >> 4, col = lane & 15;

  int afo[8], bfo[4];
#pragma unroll
  for (int i = 0; i < 8; ++i)
    afo[i] = wm * 8192 + row16 * 1024 + (i * 16 + col) * 8;
#pragma unroll
  for (int i = 0; i < 4; ++i)
    bfo[i] = row16 * 2048 + (wn * 64 + i * 16 + col) * 8;

  const f32x4 zero = {0.f, 0.f, 0.f, 0.f};
  f32x4 acc[8][4];
#pragma unroll
  for (int i = 0; i < 8; ++i)
#pragma unroll
    for (int j = 0; j < 4; ++j) acc[i][j] = zero;

  f16x8 af[4][2], bf[4][2];

#define DN_LOAD_A(AP, mh) \
  _Pragma("unroll") for (int mi_ = 0; mi_ < 4; ++mi_) \
  _Pragma("unroll") for (int ks_ = 0; ks_ < 2; ++ks_) \
    af[mi_][ks_] = *(const f16x8*)((AP) + afo[(mh) * 4 + mi_] + ks_ * 4096);

#define DN_LOAD_B(BP, nh) \
  _Pragma("unroll") for (int ni_ = 0; ni_ < 2; ++ni_) \
  _Pragma("unroll") for (int ks_ = 0; ks_ < 2; ++ks_) \
    bf[(nh) * 2 + ni_][ks_] = *(const f16x8*)((BP) + bfo[(nh) * 2 + ni_] + ks_ * 8192);

#define DN_MFMA(mh, nh) \
  _Pragma("unroll") for (int mi_ = 0; mi_ < 4; ++mi_) \
  _Pragma("unroll") for (int ni_ = 0; ni_ < 2; ++ni_) \
  _Pragma("unroll") for (int ks_ = 0; ks_ < 2; ++ks_) \
    acc[(mh) * 4 + mi_][(nh) * 2 + ni_] = __builtin_amdgcn_mfma_f32_16x16x32_f16( \
        af[mi_][ks_], bf[(nh) * 2 + ni_][ks_], acc[(mh) * 4 + mi_][(nh) * 2 + ni_], 0, 0, 0);

#define DN_STAGE_A(AP, kt) do { const int kt_ = (kt); \
  _Pragma("unroll") for (int q_ = 0; q_ < 4; ++q_) { \
    const int i_ = q_ * 512 + tid; \
    async_copy16(hs + (size_t)(((2 * mt + (i_ >> 10)) * 704 + kt_ * 8 + ((i_ >> 7) & 7)) * 128 + (i_ & 127)) * 8, \
                 (char*)(AP) + q_ * 8192 + wave * 1024); } } while (0)

#define DN_STAGE_B(BP, kt) do { const int kt_ = (kt); \
  _Pragma("unroll") for (int q_ = 0; q_ < 4; ++q_) { \
    const int i_ = q_ * 512 + tid; \
    async_copy16(wd + (size_t)((kt_ * 8 + (i_ >> 8)) * HIDDEN + nt * 256 + (i_ & 255)) * 8, \
                 (char*)(BP) + q_ * 8192 + wave * 1024); } } while (0)

  // prologue: tile0 -> buf0 (8 loads), tile1 -> buf1 (8 loads)
  DN_STAGE_B(B0, 0); DN_STAGE_A(A0, 0);
  DN_STAGE_B(B1, 1); DN_STAGE_A(A1, 1);
  WAITVM(8);          // tile0 complete; tile1's 8 stay in flight
  BAR; SB0;

  for (int t2 = 0; t2 < 44; ++t2) {
    const int e2 = (2 * t2 + 2 < 88) ? 2 * t2 + 2 : 87;
    const int o2 = (2 * t2 + 3 < 88) ? 2 * t2 + 3 : 87;
    // ph1: E Q(0,0)
    DN_LOAD_A(A0, 0); DN_LOAD_B(B0, 0);
    BAR; LGKM0; PRIO(1); DN_MFMA(0, 0); PRIO(0); BAR; SB0;
    // ph2: E Q(0,1)
    DN_LOAD_B(B0, 1);
    BAR; LGKM0; PRIO(1); DN_MFMA(0, 1); PRIO(0); BAR; SB0;
    // ph3: E Q(1,0) (B nh0 kept in regs)
    DN_LOAD_A(A0, 1); DN_STAGE_B(B0, e2);
    BAR; LGKM0; PRIO(1); DN_MFMA(1, 0); PRIO(0); BAR; SB0;
    // ph4: E Q(1,1) + counted wait (tile O resident)
    DN_STAGE_A(A0, e2);
    BAR; LGKM0; PRIO(1); DN_MFMA(1, 1); PRIO(0); WAITVM(8); BAR; SB0;
    // ph5: O Q(0,0)
    DN_LOAD_A(A1, 0); DN_LOAD_B(B1, 0);
    BAR; LGKM0; PRIO(1); DN_MFMA(0, 0); PRIO(0); BAR; SB0;
    // ph6: O Q(0,1)
    DN_LOAD_B(B1, 1);
    BAR; LGKM0; PRIO(1); DN_MFMA(0, 1); PRIO(0); BAR; SB0;
    // ph7: O Q(1,0)
    DN_LOAD_A(A1, 1); DN_STAGE_B(B1, o2);
    BAR; LGKM0; PRIO(1); DN_MFMA(1, 0); PRIO(0); BAR; SB0;
    // ph8: O Q(1,1) + counted wait (tile E+2 resident)
    DN_STAGE_A(A1, o2);
    BAR; LGKM0; PRIO(1); DN_MFMA(1, 1); PRIO(0); WAITVM(8); BAR; SB0;
  }
  WAITVM(0);

#pragma unroll
  for (int mi = 0; mi < 8; ++mi)
#pragma unroll
    for (int ni = 0; ni < 4; ++ni) {
      const int n = nt * 256 + wn * 64 + ni * 16 + col;
#pragma unroll
      for (int r = 0; r < 4; ++r) {
        const int m = mt * 256 + wm * 128 + mi * 16 + row16 * 4 + r;
        out[(size_t)m * HIDDEN + n] = acc[mi][ni][r];
      }
    }
#undef DN_LOAD_A
#undef DN_LOAD_B
#undef DN_MFMA
#undef DN_STAGE_A
#undef DN_STAGE_B
}

extern "C" void kernel_launch(void* const* d_in, const int* in_sizes, int n_in,
                              void* d_out, int out_size, void* d_ws, size_t ws_size,
                              hipStream_t stream) {
  (void)in_sizes; (void)n_in; (void)out_size; (void)ws_size;
  const float*        x  = (const float*)d_in[0];
  const unsigned int* gq = (const unsigned int*)d_in[1];
  const unsigned int* gz = (const unsigned int*)d_in[2];
  const float*        gs = (const float*)d_in[3];
  const unsigned int* uq = (const unsigned int*)d_in[4];
  const unsigned int* uz = (const unsigned int*)d_in[5];
  const float*        us = (const float*)d_in[6];
  const unsigned int* dq = (const unsigned int*)d_in[7];
  const unsigned int* dz = (const unsigned int*)d_in[8];
  const float*        ds = (const float*)d_in[9];
  float* out = (float*)d_out;

  // workspace layout (bytes):
  // xs  [0, 32MB)   x staged f16
  // wgd [32MB, +22MB) wud [+22MB) wdd [+22MB)  dequanted weights, staged f16
  // hs  [+88MB)     h staged f16   -> total ~186MB
  char* ws = (char*)d_ws;
  _Float16* xs  = (_Float16*)ws;
  _Float16* wgd = (_Float16*)(ws + (size_t)TOKENS * HIDDEN * 2);
  _Float16* wud = wgd + (size_t)HIDDEN * INTER;
  _Float16* wdd = wud + (size_t)HIDDEN * INTER;
  _Float16* hs  = wdd + (size_t)INTER * HIDDEN;

  static bool attr_set = false;
  if (!attr_set) {
    hipFuncSetAttribute((const void*)k_gemm_gateup,
                        hipFuncAttributeMaxDynamicSharedMemorySize, 131072);
    hipFuncSetAttribute((const void*)k_gemm_down,
                        hipFuncAttributeMaxDynamicSharedMemorySize, 131072);
    attr_set = true;
  }

  k_convert_x<<<dim3(HIDDEN / 8, TOKENS / 128), 128, 0, stream>>>(x, xs);
  k_dequant<<<dim3(INTER / 256, HIDDEN / 8), 256, 0, stream>>>(gq, gz, gs, wgd, INTER, INTER / 8);
  k_dequant<<<dim3(INTER / 256, HIDDEN / 8), 256, 0, stream>>>(uq, uz, us, wud, INTER, INTER / 8);
  k_dequant<<<dim3(HIDDEN / 256, INTER / 8), 256, 0, stream>>>(dq, dz, ds, wdd, HIDDEN, HIDDEN / 8);
  k_gemm_gateup<<<dim3(1408), 512, 131072, stream>>>(xs, wgd, wud, hs);
  k_gemm_down<<<dim3(256), 512, 131072, stream>>>(hs, wdd, out);
}